// Round 1
// baseline (169.818 us; speedup 1.0000x reference)
//
#include <hip/hip_runtime.h>
#include <hip/hip_bf16.h>

typedef __attribute__((ext_vector_type(8))) short short8;
typedef __attribute__((ext_vector_type(4))) float f32x4;

#define L2E 1.44269504088896340736f

__device__ __forceinline__ float ipow(float x, int e) {
    float r = 1.f;
    for (int i = 0; i < e; ++i) r *= x;
    return r;
}

// Q=32768, N=1024, D=3, C=32, P=4
// Block: 256 threads = 4 waves; 64 q-rows per block; wave wv owns rows [wv*16, wv*16+16) x all 32 c.
// LDS: w_lds  [32 c][1024 n] bf16, byte = c*2048 + ((2n) ^ ((c&7)<<4))            : 65536 B
//      a_lds  per-wave [16 m][64 k] bf16, byte = wv*2048 + m*128 + ((2k)^((m&7)<<4)): 8192 B
//      q_lds  [64][3] f32                                                          : 768 B
// total 74496 B -> 2 blocks/CU (8 waves/CU).
__global__ __launch_bounds__(256, 2)
void rbf_fused(const float* __restrict__ q_pos,
               const float* __restrict__ data_pos,
               const float* __restrict__ w,
               const float* __restrict__ cmat,
               const int* __restrict__ poly_power,
               float* __restrict__ out_val,    // [Q,32]
               float* __restrict__ out_kd,     // [Q,1024]
               float* __restrict__ out_poly)   // [Q,4]
{
    __shared__ __align__(16) unsigned char smem[65536 + 8192 + 768];
    unsigned char* const w_lds = smem;
    unsigned char* const a_lds = smem + 65536;
    float* const q_lds = (float*)(smem + 65536 + 8192);

    const int t  = threadIdx.x;
    const int l  = t & 63;
    const int wv = t >> 6;
    const int q0 = blockIdx.x * 64;

    // ---- stage w -> LDS bf16, transposed [c][n], XOR-swizzled ----
    for (int j = 0; j < 128; ++j) {
        int i = t + 256 * j;              // flat index over [n][c], coalesced global read
        int n = i >> 5, cc = i & 31;
        __hip_bfloat16 h = __float2bfloat16(w[i]);
        *(__hip_bfloat16*)(w_lds + cc * 2048 + ((2 * n) ^ ((cc & 7) << 4))) = h;
    }
    // ---- stage q tile ----
    if (t < 192) q_lds[t] = q_pos[q0 * 3 + t];
    // ---- out_poly: one element per thread over the whole grid ----
    {
        int i = blockIdx.x * 256 + t;     // covers Q*4 exactly
        int q = i >> 2, p = i & 3;
        int e0 = poly_power[p * 3 + 0], e1 = poly_power[p * 3 + 1], e2 = poly_power[p * 3 + 2];
        float x = q_pos[q * 3 + 0], y = q_pos[q * 3 + 1], z = q_pos[q * 3 + 2];
        out_poly[i] = ipow(x, e0) * ipow(y, e1) * ipow(z, e2);
    }
    __syncthreads();   // the only barrier

    // per-wave q rows into registers (wave-uniform values)
    float qx[16], qy[16], qz[16];
#pragma unroll
    for (int r = 0; r < 16; ++r) {
        int row = wv * 16 + r;
        qx[r] = q_lds[row * 3 + 0];
        qy[r] = q_lds[row * 3 + 1];
        qz[r] = q_lds[row * 3 + 2];
    }

    // ---- phase 1: row sums of exp(-r^2) ----
    float sum[16];
#pragma unroll
    for (int r = 0; r < 16; ++r) sum[r] = 0.f;
    for (int it = 0; it < 16; ++it) {
        int n = it * 64 + l;
        float px = data_pos[n * 3 + 0];
        float py = data_pos[n * 3 + 1];
        float pz = data_pos[n * 3 + 2];
#pragma unroll
        for (int r = 0; r < 16; ++r) {
            float dx = qx[r] - px, dy = qy[r] - py, dz = qz[r] - pz;
            float r2 = dx * dx + dy * dy + dz * dz;
            sum[r] += __builtin_amdgcn_exp2f(r2 * (-L2E));
        }
    }
    float inv[16];
#pragma unroll
    for (int r = 0; r < 16; ++r) {
        float s = sum[r];
        s += __shfl_xor(s, 1);  s += __shfl_xor(s, 2);  s += __shfl_xor(s, 4);
        s += __shfl_xor(s, 8);  s += __shfl_xor(s, 16); s += __shfl_xor(s, 32);
        inv[r] = 1.0f / s;
    }

    // ---- phase 2: recompute e, write normalized out_kd, build bf16 A-tile, MFMA ----
    f32x4 acc0 = {0.f, 0.f, 0.f, 0.f};
    f32x4 acc1 = {0.f, 0.f, 0.f, 0.f};

    const int arow = l & 15;               // A row / B col lane index
    const int kq   = l >> 4;               // k-quad
    const int aswz = (arow & 7) << 4;
    unsigned char* const aw = a_lds + wv * 2048;
    const int offA0 = arow * 128 + (((0 * 32 + 8 * kq) * 2) ^ aswz);
    const int offA1 = arow * 128 + (((1 * 32 + 8 * kq) * 2) ^ aswz);
    const int c0   = arow;                 // output col within ctile
    const int bswz = (c0 & 7) << 4;

    for (int ch = 0; ch < 16; ++ch) {
        int nb = ch * 64;
        int n = nb + l;
        float px = data_pos[n * 3 + 0];
        float py = data_pos[n * 3 + 1];
        float pz = data_pos[n * 3 + 2];
#pragma unroll
        for (int r = 0; r < 16; ++r) {
            float dx = qx[r] - px, dy = qy[r] - py, dz = qz[r] - pz;
            float r2 = dx * dx + dy * dy + dz * dz;
            float e  = __builtin_amdgcn_exp2f(r2 * (-L2E));
            float v  = e * inv[r];
            out_kd[(size_t)(q0 + wv * 16 + r) * 1024 + n] = v;   // coalesced 64-lane store
            *(__hip_bfloat16*)(aw + r * 128 + ((2 * l) ^ ((r & 7) << 4))) = __float2bfloat16(v);
        }
        // wave-local LDS RAW: compiler inserts lgkmcnt waits; no barrier needed
#pragma unroll
        for (int kk = 0; kk < 2; ++kk) {
            short8 afrag = *(const short8*)(aw + (kk ? offA1 : offA0));
            int n0 = nb + kk * 32 + 8 * kq;
            int boff = c0 * 2048 + ((2 * n0) ^ bswz);
            short8 b0 = *(const short8*)(w_lds + boff);
            short8 b1 = *(const short8*)(w_lds + boff + 16 * 2048);
            acc0 = __builtin_amdgcn_mfma_f32_16x16x32_bf16(afrag, b0, acc0, 0, 0, 0);
            acc1 = __builtin_amdgcn_mfma_f32_16x16x32_bf16(afrag, b1, acc1, 0, 0, 0);
        }
    }

    // ---- epilogue: add poly term (f32 exact), write out_val ----
    float cp0[4], cp1[4];
#pragma unroll
    for (int p = 0; p < 4; ++p) {
        cp0[p] = cmat[p * 32 + c0];
        cp1[p] = cmat[p * 32 + 16 + c0];
    }
    int pw[12];
#pragma unroll
    for (int i = 0; i < 12; ++i) pw[i] = poly_power[i];
#pragma unroll
    for (int r = 0; r < 4; ++r) {
        int row = kq * 4 + r;              // D row = (l>>4)*4 + reg
        float x = q_lds[(wv * 16 + row) * 3 + 0];
        float y = q_lds[(wv * 16 + row) * 3 + 1];
        float z = q_lds[(wv * 16 + row) * 3 + 2];
        float cv0 = 0.f, cv1 = 0.f;
#pragma unroll
        for (int p = 0; p < 4; ++p) {
            float pv = ipow(x, pw[p * 3]) * ipow(y, pw[p * 3 + 1]) * ipow(z, pw[p * 3 + 2]);
            cv0 += cp0[p] * pv;
            cv1 += cp1[p] * pv;
        }
        int q = q0 + wv * 16 + row;
        out_val[q * 32 + c0]      = acc0[r] + cv0;
        out_val[q * 32 + 16 + c0] = acc1[r] + cv1;
    }
}

extern "C" void kernel_launch(void* const* d_in, const int* in_sizes, int n_in,
                              void* d_out, int out_size, void* d_ws, size_t ws_size,
                              hipStream_t stream) {
    const float* q_pos      = (const float*)d_in[0];
    const float* data_pos   = (const float*)d_in[1];
    const float* w          = (const float*)d_in[2];
    const float* cmat       = (const float*)d_in[3];
    const int*   poly_power = (const int*)d_in[4];

    const int Q = in_sizes[0] / 3;          // 32768
    float* out      = (float*)d_out;
    float* out_val  = out;                  // [Q,32]
    float* out_kd   = out + (size_t)Q * 32; // [Q,1024]
    float* out_poly = out_kd + (size_t)Q * 1024; // [Q,4]

    int blocks = Q / 64;                    // 512
    rbf_fused<<<blocks, 256, 0, stream>>>(q_pos, data_pos, w, cmat, poly_power,
                                          out_val, out_kd, out_poly);
}